// Round 2
// baseline (357.712 us; speedup 1.0000x reference)
//
#include <hip/hip_runtime.h>

typedef unsigned short u16;
typedef unsigned int   u32;

using short8 = __attribute__((ext_vector_type(8))) short;
using f32x4  = __attribute__((ext_vector_type(4))) float;
using half4  = __attribute__((ext_vector_type(4))) _Float16;
using half8  = __attribute__((ext_vector_type(8))) _Float16;

// SCALE * log2(e) folded into q at the QKV epilogue
#define QSCALE 0.18033688011112042f

__device__ __forceinline__ u16 f2bf(float f) {
  u32 u = __float_as_uint(f);
  return (u16)((u + 0x8000u) >> 16);
}
__device__ __forceinline__ u16 f2h(float f) {
  _Float16 h = (_Float16)f;
  return __builtin_bit_cast(u16, h);
}

// async global->LDS DMA, 16B per lane; lds dest = wave-uniform base + lane*16
__device__ __forceinline__ void gld16(const u16* g, u16* l) {
  __builtin_amdgcn_global_load_lds(
      (const __attribute__((address_space(1))) unsigned int*)g,
      (__attribute__((address_space(3))) unsigned int*)l, 16, 0, 0);
}

// ---------------- x fp32 -> bf16, 4 elems/thread ----------------
__global__ __launch_bounds__(256) void cvt_x(const float* __restrict__ in,
                                             u16* __restrict__ out) {
  int idx = blockIdx.x * 256 + threadIdx.x;
  float4 v = reinterpret_cast<const float4*>(in)[idx];
  ushort4 o;
  o.x = f2bf(v.x); o.y = f2bf(v.y); o.z = f2bf(v.z); o.w = f2bf(v.w);
  reinterpret_cast<ushort4*>(out)[idx] = o;
}

// ---------------- fp32 [R][C] -> bf16 [C][R] (B^T layout for GEMM) ----------------
__global__ __launch_bounds__(256) void transpose_w(const float* __restrict__ in,
                                                   u16* __restrict__ out,
                                                   int R, int C) {
  __shared__ u32 s[32][33];
  int c0 = blockIdx.x * 32, r0 = blockIdx.y * 32;
  int j = threadIdx.x & 31, i0 = threadIdx.x >> 5;
#pragma unroll
  for (int p = 0; p < 4; ++p) {
    int i = i0 + p * 8;
    s[i][j] = f2bf(in[(size_t)(r0 + i) * C + c0 + j]);
  }
  __syncthreads();
#pragma unroll
  for (int p = 0; p < 4; ++p) {
    int jj = i0 + p * 8;
    out[(size_t)(c0 + jj) * R + r0 + j] = (u16)s[j][jj];
  }
}

// ---------------- bf16 MFMA GEMM: C[M,N] = A[M,K] @ Bt[N,K]^T + bias ----------------
// m97 structure, block tile (32*MT) x 128, BK=32, global_load_lds width-16
// staging with XOR-swizzled LDS. EPI==0 (MT=4): scatter qkv (q pre-scaled by
// SCALE*log2e; v written fp16 in 16-half-contiguous frag layout:
// off = ((t>>2)*16 + (d&15))*16 + (d>>4)*4 + (t&3)). EPI==1 (MT=2): fp32 C out.
template <int EPI, int MT>
__global__ __launch_bounds__(256, 3) void gemm_bt(
    const u16* __restrict__ A, const u16* __restrict__ Bt,
    const float* __restrict__ bias, float* __restrict__ c_out,
    u16* __restrict__ q_out, u16* __restrict__ k_out, u16* __restrict__ vt_out,
    int M, int N, int K) {
  __shared__ __align__(16) u16 As[32 * MT * 32];
  __shared__ __align__(16) u16 Bs[128 * 32];
  const int tid = threadIdx.x;
  const int lane = tid & 63;
  const int wv = tid >> 6;
  const int l16 = lane & 15, quad = lane >> 4;
  const int wm = wv & 1, wn = wv >> 1;
  const int bx = blockIdx.x, by = blockIdx.y;

  const u16* Ab = A + (size_t)by * (32 * MT) * K;
  const u16* Bb = Bt + (size_t)bx * 128 * K;

  const f32x4 fzero = {0.0f, 0.0f, 0.0f, 0.0f};
  f32x4 acc[MT][4];
#pragma unroll
  for (int i = 0; i < MT; ++i)
#pragma unroll
    for (int j = 0; j < 4; ++j) acc[i][j] = fzero;

  for (int k0 = 0; k0 < K; k0 += 32) {
    __syncthreads();
#pragma unroll
    for (int p = 0; p < MT / 2; ++p) {
      int id = p * 256 + tid;
      int row = id >> 2, blk = id & 3;
      int gc = k0 + ((blk ^ (row & 3)) << 3);
      gld16(Ab + (size_t)row * K + gc, &As[id << 3]);
    }
#pragma unroll
    for (int p = 0; p < 2; ++p) {
      int id = p * 256 + tid;
      int row = id >> 2, blk = id & 3;
      int gc = k0 + ((blk ^ (row & 3)) << 3);
      gld16(Bb + (size_t)row * K + gc, &Bs[id << 3]);
    }
    __syncthreads();
    short8 af[MT], bfr[4];
#pragma unroll
    for (int mi = 0; mi < MT; ++mi) {
      int row = wm * (MT * 16) + mi * 16 + l16;
      af[mi] = *reinterpret_cast<const short8*>(&As[row * 32 + ((quad ^ (row & 3)) << 3)]);
    }
#pragma unroll
    for (int ni = 0; ni < 4; ++ni) {
      int row = wn * 64 + ni * 16 + l16;
      bfr[ni] = *reinterpret_cast<const short8*>(&Bs[row * 32 + ((quad ^ (row & 3)) << 3)]);
    }
#pragma unroll
    for (int mi = 0; mi < MT; ++mi)
#pragma unroll
      for (int ni = 0; ni < 4; ++ni)
        acc[mi][ni] = __builtin_amdgcn_mfma_f32_16x16x32_bf16(af[mi], bfr[ni], acc[mi][ni], 0, 0, 0);
  }

  // epilogue: C row = quad*4+r (A dim), col = l16 (B dim)
#pragma unroll
  for (int mi = 0; mi < MT; ++mi)
#pragma unroll
    for (int ni = 0; ni < 4; ++ni) {
      int col = bx * 128 + wn * 64 + ni * 16 + l16;
      float bv = bias[col];
      int row0 = by * (32 * MT) + wm * (MT * 16) + mi * 16 + quad * 4;
      if (EPI == 1) {
#pragma unroll
        for (int r = 0; r < 4; ++r)
          c_out[(size_t)(row0 + r) * N + col] = acc[mi][ni][r] + bv;
      } else {
        int which = col >> 10, rem = col & 1023;
        int h = rem >> 6, d = rem & 63;
        int b = row0 >> 11, sq0 = row0 & 2047;
        int bh = (b << 4) + h;
        if (which == 2) {
          // V fp16 frag layout: 4 consecutive t -> one 8B store
          ushort4 pk;
          pk.x = f2h(acc[mi][ni][0] + bv);
          pk.y = f2h(acc[mi][ni][1] + bv);
          pk.z = f2h(acc[mi][ni][2] + bv);
          pk.w = f2h(acc[mi][ni][3] + bv);
          size_t off = (size_t)bh * 131072 +
                       (((sq0 >> 2) * 16 + (d & 15)) * 16 + ((d >> 4) << 2));
          *reinterpret_cast<ushort4*>(&vt_out[off]) = pk;
        } else {
          size_t base = (size_t)(bh * 2048 + sq0) * 64 + d;
#pragma unroll
          for (int r = 0; r < 4; ++r) {
            float val = acc[mi][ni][r] + bv;
            if (which == 0) q_out[base + r * 64] = f2bf(val * QSCALE);
            else            k_out[base + r * 64] = f2bf(val);
          }
        }
      }
    }
}

// ---------------- flash attention (register-direct K/V, zero-barrier loop) ----
// 64 Q rows/block, 4 waves t-split: wave w owns t-rows [w*16,w*16+16) of each
// 64-t tile for ALL 64 q. No LDS in the main loop; NO __syncthreads in loop.
// Register diet for 4 waves/SIMD residency (total <= 128 incl. 64 acc):
//  - K double-buffered (consumed at iter start, needs prefetch)
//  - V single-buffered: loaded at iter top, first consumed after QK+exp2
//    (~300 cyc own-wave slack covers the L2 hit)
//  - pa computed per-qi (short live range)
// __launch_bounds__(256,4) pins the allocator to the 128-reg budget.
__global__ __launch_bounds__(256, 4) void attn(
    const u16* __restrict__ q_buf, const u16* __restrict__ k_buf,
    const u16* __restrict__ vt_buf, u16* __restrict__ o_buf) {
  __shared__ __align__(16) float red[4][4][256];  // [w][nd][lane*4], 16 KB
  __shared__ float lred[4][16];

  const int tid = threadIdx.x;
  const int lane = tid & 63, w = tid >> 6;
  const int l16 = lane & 15, quad = lane >> 4;
  const int bh = blockIdx.x, q0 = blockIdx.y * 64;

  const u16* qg = q_buf + (size_t)bh * 131072 + q0 * 64;
  const u16* kp = k_buf + (size_t)bh * 131072 + (w * 16 + l16) * 64 + quad * 8;
  const u16* vp = vt_buf + (size_t)bh * 131072 + ((w * 4 + quad) * 16 + l16) * 16;

  // Q B-frags (loop-invariant): per qi tile n=q=l16, k = kk*32 + quad*8 + j
  short8 qb[4][2];
#pragma unroll
  for (int qi = 0; qi < 4; ++qi)
#pragma unroll
    for (int kk = 0; kk < 2; ++kk)
      qb[qi][kk] = *reinterpret_cast<const short8*>(
          qg + (qi * 16 + l16) * 64 + kk * 32 + quad * 8);

  const f32x4 fzero = {0.0f, 0.0f, 0.0f, 0.0f};
  f32x4 o_acc[4][4];
  float l_acc[4] = {0.f, 0.f, 0.f, 0.f};
#pragma unroll
  for (int qi = 0; qi < 4; ++qi)
#pragma unroll
    for (int nd = 0; nd < 4; ++nd) o_acc[qi][nd] = fzero;

  // prologue: load tile-0 K frags
  short8 ka[2][2];
  ka[0][0] = *reinterpret_cast<const short8*>(kp);
  ka[0][1] = *reinterpret_cast<const short8*>(kp + 32);

#pragma unroll 2
  for (int i = 0; i < 32; ++i) {
    const int buf = i & 1, nb = buf ^ 1;

    // current-iter V (single-buffered; consumed only after QK+exp2)
    half8 v0 = *reinterpret_cast<const half8*>(vp);
    half8 v1 = *reinterpret_cast<const half8*>(vp + 8);
    vp += 4096;

    if (i + 1 < 32) {  // prefetch next tile's K frags
      const u16* kn = kp + (size_t)4096;
      ka[nb][0] = *reinterpret_cast<const short8*>(kn);
      ka[nb][1] = *reinterpret_cast<const short8*>(kn + 32);
      kp = kn;
    }

    short8 k0 = ka[buf][0], k1 = ka[buf][1];
    half4 vb0 = __builtin_shufflevector(v0, v0, 0, 1, 2, 3);
    half4 vb1 = __builtin_shufflevector(v0, v0, 4, 5, 6, 7);
    half4 vb2 = __builtin_shufflevector(v1, v1, 0, 1, 2, 3);
    half4 vb3 = __builtin_shufflevector(v1, v1, 4, 5, 6, 7);

    // per qi: S^T = K.Q^T -> P = exp2 -> O_partial += P.V  (pa short-lived)
#pragma unroll
    for (int qi = 0; qi < 4; ++qi) {
      f32x4 s = __builtin_amdgcn_mfma_f32_16x16x32_bf16(k0, qb[qi][0], fzero, 0, 0, 0);
      s = __builtin_amdgcn_mfma_f32_16x16x32_bf16(k1, qb[qi][1], s, 0, 0, 0);
      float p0 = __builtin_amdgcn_exp2f(s[0]);
      float p1 = __builtin_amdgcn_exp2f(s[1]);
      float p2 = __builtin_amdgcn_exp2f(s[2]);
      float p3 = __builtin_amdgcn_exp2f(s[3]);
      l_acc[qi] += (p0 + p1) + (p2 + p3);
      half4 pa;
      pa[0] = (_Float16)p0; pa[1] = (_Float16)p1;
      pa[2] = (_Float16)p2; pa[3] = (_Float16)p3;
      o_acc[qi][0] = __builtin_amdgcn_mfma_f32_16x16x16f16(pa, vb0, o_acc[qi][0], 0, 0, 0);
      o_acc[qi][1] = __builtin_amdgcn_mfma_f32_16x16x16f16(pa, vb1, o_acc[qi][1], 0, 0, 0);
      o_acc[qi][2] = __builtin_amdgcn_mfma_f32_16x16x16f16(pa, vb2, o_acc[qi][2], 0, 0, 0);
      o_acc[qi][3] = __builtin_amdgcn_mfma_f32_16x16x16f16(pa, vb3, o_acc[qi][3], 0, 0, 0);
    }
  }

  // l: reduce across quads -> every lane holds this wave's l for q=l16
#pragma unroll
  for (int qi = 0; qi < 4; ++qi) {
    l_acc[qi] += __shfl_xor(l_acc[qi], 16, 64);
    l_acc[qi] += __shfl_xor(l_acc[qi], 32, 64);
  }

  // cross-wave O/l reduction per qi-phase through LDS
  const int b = bh >> 4, h = bh & 15;
#pragma unroll
  for (int qi = 0; qi < 4; ++qi) {
#pragma unroll
    for (int nd = 0; nd < 4; ++nd)
      *reinterpret_cast<f32x4*>(&red[w][nd][lane * 4]) = o_acc[qi][nd];
    if (lane < 16) lred[w][lane] = l_acc[qi];
    __syncthreads();
    // wave w reduces & writes d-columns [w*16, w*16+16)
    f32x4 os = fzero, lv = fzero;
#pragma unroll
    for (int wp = 0; wp < 4; ++wp) {
      os += *reinterpret_cast<const f32x4*>(&red[wp][w][lane * 4]);
      lv += *reinterpret_cast<const f32x4*>(&lred[wp][quad * 4]);
    }
#pragma unroll
    for (int r = 0; r < 4; ++r) {
      int sq = q0 + qi * 16 + quad * 4 + r;
      o_buf[(size_t)(b * 2048 + sq) * 1024 + h * 64 + w * 16 + l16] =
          f2bf(os[r] / lv[r]);
    }
    __syncthreads();
  }
}

extern "C" void kernel_launch(void* const* d_in, const int* in_sizes, int n_in,
                              void* d_out, int out_size, void* d_ws, size_t ws_size,
                              hipStream_t stream) {
  (void)in_sizes; (void)n_in; (void)out_size; (void)ws_size;
  const float* x     = (const float*)d_in[0];
  const float* W_qkv = (const float*)d_in[1];
  const float* b_qkv = (const float*)d_in[2];
  const float* W_out = (const float*)d_in[3];
  const float* b_out = (const float*)d_in[4];
  float* out = (float*)d_out;

  // workspace layout (48 MB total)
  char* ws = (char*)d_ws;
  u16* x_bf   = (u16*)(ws);              //  8 MB  [4096][1024] bf16
  u16* wqkv_t = (u16*)(ws + 8388608);    //  6 MB  [3072][1024] bf16
  u16* wout_t = (u16*)(ws + 14680064);   //  2 MB  [1024][1024] bf16
  u16* q_buf  = (u16*)(ws + 16777216);   //  8 MB  [32][2048][64] bf16
  u16* k_buf  = (u16*)(ws + 25165824);   //  8 MB  [32][2048][64] bf16
  u16* vt_buf = (u16*)(ws + 33554432);   //  8 MB  [32] V-frag fp16 layout
  u16* o_bf   = (u16*)(ws + 41943040);   //  8 MB  [4096][1024] bf16

  cvt_x<<<4096, 256, 0, stream>>>(x, x_bf);
  transpose_w<<<dim3(96, 32), 256, 0, stream>>>(W_qkv, wqkv_t, 1024, 3072);
  transpose_w<<<dim3(32, 32), 256, 0, stream>>>(W_out, wout_t, 1024, 1024);
  gemm_bt<0, 4><<<dim3(24, 32), 256, 0, stream>>>(x_bf, wqkv_t, b_qkv, nullptr,
                                                  q_buf, k_buf, vt_buf, 4096, 3072, 1024);
  attn<<<dim3(32, 32), 256, 0, stream>>>(q_buf, k_buf, vt_buf, o_bf);
  gemm_bt<1, 2><<<dim3(8, 64), 256, 0, stream>>>(o_bf, wout_t, b_out, out,
                                                 nullptr, nullptr, nullptr, 4096, 1024, 1024);
}

// Round 3
// 220.483 us; speedup vs baseline: 1.6224x; 1.6224x over previous
//
#include <hip/hip_runtime.h>

typedef unsigned short u16;
typedef unsigned int   u32;

using short8 = __attribute__((ext_vector_type(8))) short;
using f32x4  = __attribute__((ext_vector_type(4))) float;
using half4  = __attribute__((ext_vector_type(4))) _Float16;
using half8  = __attribute__((ext_vector_type(8))) _Float16;

// SCALE * log2(e) folded into q at the QKV epilogue
#define QSCALE 0.18033688011112042f

__device__ __forceinline__ u16 f2bf(float f) {
  u32 u = __float_as_uint(f);
  return (u16)((u + 0x8000u) >> 16);
}
__device__ __forceinline__ u16 f2h(float f) {
  _Float16 h = (_Float16)f;
  return __builtin_bit_cast(u16, h);
}

// async global->LDS DMA, 16B per lane; lds dest = wave-uniform base + lane*16
__device__ __forceinline__ void gld16(const u16* g, u16* l) {
  __builtin_amdgcn_global_load_lds(
      (const __attribute__((address_space(1))) unsigned int*)g,
      (__attribute__((address_space(3))) unsigned int*)l, 16, 0, 0);
}

// ---------------- x fp32 -> bf16, 4 elems/thread ----------------
__global__ __launch_bounds__(256) void cvt_x(const float* __restrict__ in,
                                             u16* __restrict__ out) {
  int idx = blockIdx.x * 256 + threadIdx.x;
  float4 v = reinterpret_cast<const float4*>(in)[idx];
  ushort4 o;
  o.x = f2bf(v.x); o.y = f2bf(v.y); o.z = f2bf(v.z); o.w = f2bf(v.w);
  reinterpret_cast<ushort4*>(out)[idx] = o;
}

// ---------------- fp32 [R][C] -> bf16 [C][R] (B^T layout for GEMM) ----------------
__global__ __launch_bounds__(256) void transpose_w(const float* __restrict__ in,
                                                   u16* __restrict__ out,
                                                   int R, int C) {
  __shared__ u32 s[32][33];
  int c0 = blockIdx.x * 32, r0 = blockIdx.y * 32;
  int j = threadIdx.x & 31, i0 = threadIdx.x >> 5;
#pragma unroll
  for (int p = 0; p < 4; ++p) {
    int i = i0 + p * 8;
    s[i][j] = f2bf(in[(size_t)(r0 + i) * C + c0 + j]);
  }
  __syncthreads();
#pragma unroll
  for (int p = 0; p < 4; ++p) {
    int jj = i0 + p * 8;
    out[(size_t)(c0 + jj) * R + r0 + j] = (u16)s[j][jj];
  }
}

// ---------------- bf16 MFMA GEMM: C[M,N] = A[M,K] @ Bt[N,K]^T + bias ----------------
// m97 structure, block tile (32*MT) x 128, BK=32, global_load_lds width-16
// staging with XOR-swizzled LDS. EPI==0 (MT=4): scatter qkv (q pre-scaled by
// SCALE*log2e; v written fp16 in 16-half-contiguous frag layout:
// off = ((t>>2)*16 + (d&15))*16 + (d>>4)*4 + (t&3)). EPI==1 (MT=2): fp32 C out.
template <int EPI, int MT>
__global__ __launch_bounds__(256, 3) void gemm_bt(
    const u16* __restrict__ A, const u16* __restrict__ Bt,
    const float* __restrict__ bias, float* __restrict__ c_out,
    u16* __restrict__ q_out, u16* __restrict__ k_out, u16* __restrict__ vt_out,
    int M, int N, int K) {
  __shared__ __align__(16) u16 As[32 * MT * 32];
  __shared__ __align__(16) u16 Bs[128 * 32];
  const int tid = threadIdx.x;
  const int lane = tid & 63;
  const int wv = tid >> 6;
  const int l16 = lane & 15, quad = lane >> 4;
  const int wm = wv & 1, wn = wv >> 1;
  const int bx = blockIdx.x, by = blockIdx.y;

  const u16* Ab = A + (size_t)by * (32 * MT) * K;
  const u16* Bb = Bt + (size_t)bx * 128 * K;

  const f32x4 fzero = {0.0f, 0.0f, 0.0f, 0.0f};
  f32x4 acc[MT][4];
#pragma unroll
  for (int i = 0; i < MT; ++i)
#pragma unroll
    for (int j = 0; j < 4; ++j) acc[i][j] = fzero;

  for (int k0 = 0; k0 < K; k0 += 32) {
    __syncthreads();
#pragma unroll
    for (int p = 0; p < MT / 2; ++p) {
      int id = p * 256 + tid;
      int row = id >> 2, blk = id & 3;
      int gc = k0 + ((blk ^ (row & 3)) << 3);
      gld16(Ab + (size_t)row * K + gc, &As[id << 3]);
    }
#pragma unroll
    for (int p = 0; p < 2; ++p) {
      int id = p * 256 + tid;
      int row = id >> 2, blk = id & 3;
      int gc = k0 + ((blk ^ (row & 3)) << 3);
      gld16(Bb + (size_t)row * K + gc, &Bs[id << 3]);
    }
    __syncthreads();
    short8 af[MT], bfr[4];
#pragma unroll
    for (int mi = 0; mi < MT; ++mi) {
      int row = wm * (MT * 16) + mi * 16 + l16;
      af[mi] = *reinterpret_cast<const short8*>(&As[row * 32 + ((quad ^ (row & 3)) << 3)]);
    }
#pragma unroll
    for (int ni = 0; ni < 4; ++ni) {
      int row = wn * 64 + ni * 16 + l16;
      bfr[ni] = *reinterpret_cast<const short8*>(&Bs[row * 32 + ((quad ^ (row & 3)) << 3)]);
    }
#pragma unroll
    for (int mi = 0; mi < MT; ++mi)
#pragma unroll
      for (int ni = 0; ni < 4; ++ni)
        acc[mi][ni] = __builtin_amdgcn_mfma_f32_16x16x32_bf16(af[mi], bfr[ni], acc[mi][ni], 0, 0, 0);
  }

  // epilogue: C row = quad*4+r (A dim), col = l16 (B dim)
#pragma unroll
  for (int mi = 0; mi < MT; ++mi)
#pragma unroll
    for (int ni = 0; ni < 4; ++ni) {
      int col = bx * 128 + wn * 64 + ni * 16 + l16;
      float bv = bias[col];
      int row0 = by * (32 * MT) + wm * (MT * 16) + mi * 16 + quad * 4;
      if (EPI == 1) {
#pragma unroll
        for (int r = 0; r < 4; ++r)
          c_out[(size_t)(row0 + r) * N + col] = acc[mi][ni][r] + bv;
      } else {
        int which = col >> 10, rem = col & 1023;
        int h = rem >> 6, d = rem & 63;
        int b = row0 >> 11, sq0 = row0 & 2047;
        int bh = (b << 4) + h;
        if (which == 2) {
          // V fp16 frag layout: 4 consecutive t -> one 8B store
          ushort4 pk;
          pk.x = f2h(acc[mi][ni][0] + bv);
          pk.y = f2h(acc[mi][ni][1] + bv);
          pk.z = f2h(acc[mi][ni][2] + bv);
          pk.w = f2h(acc[mi][ni][3] + bv);
          size_t off = (size_t)bh * 131072 +
                       (((sq0 >> 2) * 16 + (d & 15)) * 16 + ((d >> 4) << 2));
          *reinterpret_cast<ushort4*>(&vt_out[off]) = pk;
        } else {
          size_t base = (size_t)(bh * 2048 + sq0) * 64 + d;
#pragma unroll
          for (int r = 0; r < 4; ++r) {
            float val = acc[mi][ni][r] + bv;
            if (which == 0) q_out[base + r * 64] = f2bf(val * QSCALE);
            else            k_out[base + r * 64] = f2bf(val);
          }
        }
      }
    }
}

// ---------------- flash attention (register-direct K/V, zero-barrier loop) ----
// 32 Q rows/block (qi=2), 4 waves t-split: wave w owns t-rows [w*16,w*16+16)
// of each 64-t tile for ALL 32 q. No LDS / no __syncthreads in the main loop.
// Halving the Q tile halves the accumulator (32 regs) so total regs ~100 fit
// the (256,4) budget WITHOUT spilling -> 4 waves/SIMD resident, and grid
// (32,64)=2048 blocks = 8/CU packs into exactly two clean 4-resident batches
// (the 64q version ran 3-resident with a 25% straggler tail).
//  - K double-buffered (consumed at iter start)
//  - V single-buffered (consumed after QK+exp2; own-wave slack + TLP covers L2)
__global__ __launch_bounds__(256, 4) void attn(
    const u16* __restrict__ q_buf, const u16* __restrict__ k_buf,
    const u16* __restrict__ vt_buf, u16* __restrict__ o_buf) {
  __shared__ __align__(16) float red[4][4][256];  // [w][nd][lane*4], 16 KB
  __shared__ float lred[4][16];

  const int tid = threadIdx.x;
  const int lane = tid & 63, w = tid >> 6;
  const int l16 = lane & 15, quad = lane >> 4;
  const int bh = blockIdx.x, q0 = blockIdx.y * 32;

  const u16* qg = q_buf + (size_t)bh * 131072 + q0 * 64;
  const u16* kp = k_buf + (size_t)bh * 131072 + (w * 16 + l16) * 64 + quad * 8;
  const u16* vp = vt_buf + (size_t)bh * 131072 + ((w * 4 + quad) * 16 + l16) * 16;

  // Q B-frags (loop-invariant): per qi tile n=q=l16, k = kk*32 + quad*8 + j
  short8 qb[2][2];
#pragma unroll
  for (int qi = 0; qi < 2; ++qi)
#pragma unroll
    for (int kk = 0; kk < 2; ++kk)
      qb[qi][kk] = *reinterpret_cast<const short8*>(
          qg + (qi * 16 + l16) * 64 + kk * 32 + quad * 8);

  const f32x4 fzero = {0.0f, 0.0f, 0.0f, 0.0f};
  f32x4 o_acc[2][4];
  float l_acc[2] = {0.f, 0.f};
#pragma unroll
  for (int qi = 0; qi < 2; ++qi)
#pragma unroll
    for (int nd = 0; nd < 4; ++nd) o_acc[qi][nd] = fzero;

  // prologue: load tile-0 K frags
  short8 ka[2][2];
  ka[0][0] = *reinterpret_cast<const short8*>(kp);
  ka[0][1] = *reinterpret_cast<const short8*>(kp + 32);

#pragma unroll 2
  for (int i = 0; i < 32; ++i) {
    const int buf = i & 1, nb = buf ^ 1;

    // current-iter V (single-buffered; consumed only after QK+exp2)
    half8 v0 = *reinterpret_cast<const half8*>(vp);
    half8 v1 = *reinterpret_cast<const half8*>(vp + 8);
    vp += 4096;

    if (i + 1 < 32) {  // prefetch next tile's K frags
      const u16* kn = kp + (size_t)4096;
      ka[nb][0] = *reinterpret_cast<const short8*>(kn);
      ka[nb][1] = *reinterpret_cast<const short8*>(kn + 32);
      kp = kn;
    }

    short8 k0 = ka[buf][0], k1 = ka[buf][1];
    half4 vb0 = __builtin_shufflevector(v0, v0, 0, 1, 2, 3);
    half4 vb1 = __builtin_shufflevector(v0, v0, 4, 5, 6, 7);
    half4 vb2 = __builtin_shufflevector(v1, v1, 0, 1, 2, 3);
    half4 vb3 = __builtin_shufflevector(v1, v1, 4, 5, 6, 7);

    // per qi: S^T = K.Q^T -> P = exp2 -> O_partial += P.V  (pa short-lived)
#pragma unroll
    for (int qi = 0; qi < 2; ++qi) {
      f32x4 s = __builtin_amdgcn_mfma_f32_16x16x32_bf16(k0, qb[qi][0], fzero, 0, 0, 0);
      s = __builtin_amdgcn_mfma_f32_16x16x32_bf16(k1, qb[qi][1], s, 0, 0, 0);
      float p0 = __builtin_amdgcn_exp2f(s[0]);
      float p1 = __builtin_amdgcn_exp2f(s[1]);
      float p2 = __builtin_amdgcn_exp2f(s[2]);
      float p3 = __builtin_amdgcn_exp2f(s[3]);
      l_acc[qi] += (p0 + p1) + (p2 + p3);
      half4 pa;
      pa[0] = (_Float16)p0; pa[1] = (_Float16)p1;
      pa[2] = (_Float16)p2; pa[3] = (_Float16)p3;
      o_acc[qi][0] = __builtin_amdgcn_mfma_f32_16x16x16f16(pa, vb0, o_acc[qi][0], 0, 0, 0);
      o_acc[qi][1] = __builtin_amdgcn_mfma_f32_16x16x16f16(pa, vb1, o_acc[qi][1], 0, 0, 0);
      o_acc[qi][2] = __builtin_amdgcn_mfma_f32_16x16x16f16(pa, vb2, o_acc[qi][2], 0, 0, 0);
      o_acc[qi][3] = __builtin_amdgcn_mfma_f32_16x16x16f16(pa, vb3, o_acc[qi][3], 0, 0, 0);
    }
  }

  // l: reduce across quads -> every lane holds this wave's l for q=l16
#pragma unroll
  for (int qi = 0; qi < 2; ++qi) {
    l_acc[qi] += __shfl_xor(l_acc[qi], 16, 64);
    l_acc[qi] += __shfl_xor(l_acc[qi], 32, 64);
  }

  // cross-wave O/l reduction per qi-phase through LDS
  const int b = bh >> 4, h = bh & 15;
#pragma unroll
  for (int qi = 0; qi < 2; ++qi) {
#pragma unroll
    for (int nd = 0; nd < 4; ++nd)
      *reinterpret_cast<f32x4*>(&red[w][nd][lane * 4]) = o_acc[qi][nd];
    if (lane < 16) lred[w][lane] = l_acc[qi];
    __syncthreads();
    // wave w reduces & writes d-columns [w*16, w*16+16)
    f32x4 os = fzero, lv = fzero;
#pragma unroll
    for (int wp = 0; wp < 4; ++wp) {
      os += *reinterpret_cast<const f32x4*>(&red[wp][w][lane * 4]);
      lv += *reinterpret_cast<const f32x4*>(&lred[wp][quad * 4]);
    }
#pragma unroll
    for (int r = 0; r < 4; ++r) {
      int sq = q0 + qi * 16 + quad * 4 + r;
      o_buf[(size_t)(b * 2048 + sq) * 1024 + h * 64 + w * 16 + l16] =
          f2bf(os[r] / lv[r]);
    }
    __syncthreads();
  }
}

extern "C" void kernel_launch(void* const* d_in, const int* in_sizes, int n_in,
                              void* d_out, int out_size, void* d_ws, size_t ws_size,
                              hipStream_t stream) {
  (void)in_sizes; (void)n_in; (void)out_size; (void)ws_size;
  const float* x     = (const float*)d_in[0];
  const float* W_qkv = (const float*)d_in[1];
  const float* b_qkv = (const float*)d_in[2];
  const float* W_out = (const float*)d_in[3];
  const float* b_out = (const float*)d_in[4];
  float* out = (float*)d_out;

  // workspace layout (48 MB total)
  char* ws = (char*)d_ws;
  u16* x_bf   = (u16*)(ws);              //  8 MB  [4096][1024] bf16
  u16* wqkv_t = (u16*)(ws + 8388608);    //  6 MB  [3072][1024] bf16
  u16* wout_t = (u16*)(ws + 14680064);   //  2 MB  [1024][1024] bf16
  u16* q_buf  = (u16*)(ws + 16777216);   //  8 MB  [32][2048][64] bf16
  u16* k_buf  = (u16*)(ws + 25165824);   //  8 MB  [32][2048][64] bf16
  u16* vt_buf = (u16*)(ws + 33554432);   //  8 MB  [32] V-frag fp16 layout
  u16* o_bf   = (u16*)(ws + 41943040);   //  8 MB  [4096][1024] bf16

  cvt_x<<<4096, 256, 0, stream>>>(x, x_bf);
  transpose_w<<<dim3(96, 32), 256, 0, stream>>>(W_qkv, wqkv_t, 1024, 3072);
  transpose_w<<<dim3(32, 32), 256, 0, stream>>>(W_out, wout_t, 1024, 1024);
  gemm_bt<0, 4><<<dim3(24, 32), 256, 0, stream>>>(x_bf, wqkv_t, b_qkv, nullptr,
                                                  q_buf, k_buf, vt_buf, 4096, 3072, 1024);
  attn<<<dim3(32, 64), 256, 0, stream>>>(q_buf, k_buf, vt_buf, o_bf);
  gemm_bt<1, 2><<<dim3(8, 64), 256, 0, stream>>>(o_bf, wout_t, b_out, out,
                                                 nullptr, nullptr, nullptr, 4096, 1024, 1024);
}

// Round 4
// 192.904 us; speedup vs baseline: 1.8544x; 1.1430x over previous
//
#include <hip/hip_runtime.h>

typedef unsigned short u16;
typedef unsigned int   u32;

using short8 = __attribute__((ext_vector_type(8))) short;
using f32x4  = __attribute__((ext_vector_type(4))) float;
using half4  = __attribute__((ext_vector_type(4))) _Float16;
using half8  = __attribute__((ext_vector_type(8))) _Float16;

// SCALE * log2(e) folded into q at the QKV epilogue
#define QSCALE 0.18033688011112042f

__device__ __forceinline__ u16 f2bf(float f) {
  u32 u = __float_as_uint(f);
  return (u16)((u + 0x8000u) >> 16);
}
__device__ __forceinline__ u16 f2h(float f) {
  _Float16 h = (_Float16)f;
  return __builtin_bit_cast(u16, h);
}

// async global->LDS DMA, 16B per lane; lds dest = wave-uniform base + lane*16
__device__ __forceinline__ void gld16(const u16* g, u16* l) {
  __builtin_amdgcn_global_load_lds(
      (const __attribute__((address_space(1))) unsigned int*)g,
      (__attribute__((address_space(3))) unsigned int*)l, 16, 0, 0);
}

// ---------------- x fp32 -> bf16, 4 elems/thread ----------------
__global__ __launch_bounds__(256) void cvt_x(const float* __restrict__ in,
                                             u16* __restrict__ out) {
  int idx = blockIdx.x * 256 + threadIdx.x;
  float4 v = reinterpret_cast<const float4*>(in)[idx];
  ushort4 o;
  o.x = f2bf(v.x); o.y = f2bf(v.y); o.z = f2bf(v.z); o.w = f2bf(v.w);
  reinterpret_cast<ushort4*>(out)[idx] = o;
}

// ---------------- fp32 [R][C] -> bf16 [C][R] (B^T layout for GEMM) ----------------
__global__ __launch_bounds__(256) void transpose_w(const float* __restrict__ in,
                                                   u16* __restrict__ out,
                                                   int R, int C) {
  __shared__ u32 s[32][33];
  int c0 = blockIdx.x * 32, r0 = blockIdx.y * 32;
  int j = threadIdx.x & 31, i0 = threadIdx.x >> 5;
#pragma unroll
  for (int p = 0; p < 4; ++p) {
    int i = i0 + p * 8;
    s[i][j] = f2bf(in[(size_t)(r0 + i) * C + c0 + j]);
  }
  __syncthreads();
#pragma unroll
  for (int p = 0; p < 4; ++p) {
    int jj = i0 + p * 8;
    out[(size_t)(c0 + jj) * R + r0 + j] = (u16)s[j][jj];
  }
}

// ---------------- bf16 MFMA GEMM: C[M,N] = A[M,K] @ Bt[N,K]^T + bias ----------------
// m97 structure, block tile (32*MT) x 128, BK=32, global_load_lds width-16
// staging with XOR-swizzled LDS. EPI==0 (MT=4): scatter qkv (q pre-scaled by
// SCALE*log2e; v written fp16 in 16-half-contiguous frag layout:
// off = ((t>>2)*16 + (d&15))*16 + (d>>4)*4 + (t&3)). EPI==1 (MT=2): fp32 C out.
template <int EPI, int MT>
__global__ __launch_bounds__(256, 3) void gemm_bt(
    const u16* __restrict__ A, const u16* __restrict__ Bt,
    const float* __restrict__ bias, float* __restrict__ c_out,
    u16* __restrict__ q_out, u16* __restrict__ k_out, u16* __restrict__ vt_out,
    int M, int N, int K) {
  __shared__ __align__(16) u16 As[32 * MT * 32];
  __shared__ __align__(16) u16 Bs[128 * 32];
  const int tid = threadIdx.x;
  const int lane = tid & 63;
  const int wv = tid >> 6;
  const int l16 = lane & 15, quad = lane >> 4;
  const int wm = wv & 1, wn = wv >> 1;
  const int bx = blockIdx.x, by = blockIdx.y;

  const u16* Ab = A + (size_t)by * (32 * MT) * K;
  const u16* Bb = Bt + (size_t)bx * 128 * K;

  const f32x4 fzero = {0.0f, 0.0f, 0.0f, 0.0f};
  f32x4 acc[MT][4];
#pragma unroll
  for (int i = 0; i < MT; ++i)
#pragma unroll
    for (int j = 0; j < 4; ++j) acc[i][j] = fzero;

  for (int k0 = 0; k0 < K; k0 += 32) {
    __syncthreads();
#pragma unroll
    for (int p = 0; p < MT / 2; ++p) {
      int id = p * 256 + tid;
      int row = id >> 2, blk = id & 3;
      int gc = k0 + ((blk ^ (row & 3)) << 3);
      gld16(Ab + (size_t)row * K + gc, &As[id << 3]);
    }
#pragma unroll
    for (int p = 0; p < 2; ++p) {
      int id = p * 256 + tid;
      int row = id >> 2, blk = id & 3;
      int gc = k0 + ((blk ^ (row & 3)) << 3);
      gld16(Bb + (size_t)row * K + gc, &Bs[id << 3]);
    }
    __syncthreads();
    short8 af[MT], bfr[4];
#pragma unroll
    for (int mi = 0; mi < MT; ++mi) {
      int row = wm * (MT * 16) + mi * 16 + l16;
      af[mi] = *reinterpret_cast<const short8*>(&As[row * 32 + ((quad ^ (row & 3)) << 3)]);
    }
#pragma unroll
    for (int ni = 0; ni < 4; ++ni) {
      int row = wn * 64 + ni * 16 + l16;
      bfr[ni] = *reinterpret_cast<const short8*>(&Bs[row * 32 + ((quad ^ (row & 3)) << 3)]);
    }
#pragma unroll
    for (int mi = 0; mi < MT; ++mi)
#pragma unroll
      for (int ni = 0; ni < 4; ++ni)
        acc[mi][ni] = __builtin_amdgcn_mfma_f32_16x16x32_bf16(af[mi], bfr[ni], acc[mi][ni], 0, 0, 0);
  }

  // epilogue: C row = quad*4+r (A dim), col = l16 (B dim)
#pragma unroll
  for (int mi = 0; mi < MT; ++mi)
#pragma unroll
    for (int ni = 0; ni < 4; ++ni) {
      int col = bx * 128 + wn * 64 + ni * 16 + l16;
      float bv = bias[col];
      int row0 = by * (32 * MT) + wm * (MT * 16) + mi * 16 + quad * 4;
      if (EPI == 1) {
#pragma unroll
        for (int r = 0; r < 4; ++r)
          c_out[(size_t)(row0 + r) * N + col] = acc[mi][ni][r] + bv;
      } else {
        int which = col >> 10, rem = col & 1023;
        int h = rem >> 6, d = rem & 63;
        int b = row0 >> 11, sq0 = row0 & 2047;
        int bh = (b << 4) + h;
        if (which == 2) {
          // V fp16 frag layout: 4 consecutive t -> one 8B store
          ushort4 pk;
          pk.x = f2h(acc[mi][ni][0] + bv);
          pk.y = f2h(acc[mi][ni][1] + bv);
          pk.z = f2h(acc[mi][ni][2] + bv);
          pk.w = f2h(acc[mi][ni][3] + bv);
          size_t off = (size_t)bh * 131072 +
                       (((sq0 >> 2) * 16 + (d & 15)) * 16 + ((d >> 4) << 2));
          *reinterpret_cast<ushort4*>(&vt_out[off]) = pk;
        } else {
          size_t base = (size_t)(bh * 2048 + sq0) * 64 + d;
#pragma unroll
          for (int r = 0; r < 4; ++r) {
            float val = acc[mi][ni][r] + bv;
            if (which == 0) q_out[base + r * 64] = f2bf(val * QSCALE);
            else            k_out[base + r * 64] = f2bf(val);
          }
        }
      }
    }
}

// ---------------- flash attention (q-split waves, LDS-staged K/V) ----------
// 128 Q rows/block, 4 waves: wave w owns q-rows [w*32, w*32+32) and computes
// their COMPLETE output (all t). Each 64-t K/V tile is staged ONCE per block
// into LDS (K 8KB XOR-swizzled rows via pre-swizzled gld16 source; V 8KB
// frag-layout tile = contiguous 4096 u16, linear copy) and consumed by all 4
// waves via the tsub loop. This cuts K/V L2-read multiplicity 4x vs the 32q
// t-split version (16 blocks/head instead of 64) -> the measured L2-BW/latency
// wall. Per-wave accumulator stays 32 regs (32q x 64d). No cross-wave O
// reduction: each wave writes its own q rows; l needs only a quad shfl.
__global__ __launch_bounds__(256, 4) void attn(
    const u16* __restrict__ q_buf, const u16* __restrict__ k_buf,
    const u16* __restrict__ vt_buf, u16* __restrict__ o_buf) {
  __shared__ __align__(16) u16 Ks[64 * 64];  // 8 KB, rows XOR-swizzled
  __shared__ __align__(16) u16 Vs[4096];     // 8 KB, V frag-layout tile

  const int tid = threadIdx.x;
  const int lane = tid & 63, w = tid >> 6;
  const int l16 = lane & 15, quad = lane >> 4;
  const int bh = blockIdx.x, q0 = blockIdx.y * 128;

  const u16* qg = q_buf + (size_t)bh * 131072 + (q0 + w * 32) * 64;
  const u16* kg = k_buf + (size_t)bh * 131072;
  const u16* vg = vt_buf + (size_t)bh * 131072;

  // Q B-frags (loop-invariant): per qi tile col=q=l16, k = kk*32 + quad*8 + j
  short8 qb[2][2];
#pragma unroll
  for (int qi = 0; qi < 2; ++qi)
#pragma unroll
    for (int kk = 0; kk < 2; ++kk)
      qb[qi][kk] = *reinterpret_cast<const short8*>(
          qg + (qi * 16 + l16) * 64 + kk * 32 + quad * 8);

  const f32x4 fzero = {0.0f, 0.0f, 0.0f, 0.0f};
  f32x4 o_acc[2][4];
  float l_acc[2] = {0.f, 0.f};
#pragma unroll
  for (int qi = 0; qi < 2; ++qi)
#pragma unroll
    for (int nd = 0; nd < 4; ++nd) o_acc[qi][nd] = fzero;

  for (int i = 0; i < 32; ++i) {
    __syncthreads();  // all waves done reading previous tile
    // stage K tile (512 x 16B chunks, row-XOR pre-swizzled source) and
    // V tile (contiguous 8 KB) -- 2 chunks each per thread
#pragma unroll
    for (int p = 0; p < 2; ++p) {
      int id = p * 256 + tid;
      int krow = id >> 3, kblk = id & 7;
      gld16(kg + (size_t)krow * 64 + ((kblk ^ (krow & 7)) << 3), &Ks[id << 3]);
      gld16(vg + (id << 3), &Vs[id << 3]);
    }
    kg += 4096;
    vg += 4096;
    __syncthreads();  // compiler drains vmcnt before barrier -> tile ready

#pragma unroll
    for (int tsub = 0; tsub < 4; ++tsub) {
      // K A-frags: row rr = tsub*16 + l16, k-block (kk*4+quad) XOR (rr&7)
      int rr = tsub * 16 + l16;
      short8 k0f = *reinterpret_cast<const short8*>(
          &Ks[rr * 64 + ((quad ^ (rr & 7)) << 3)]);
      short8 k1f = *reinterpret_cast<const short8*>(
          &Ks[rr * 64 + (((4 + quad) ^ (rr & 7)) << 3)]);
      // V B-frags for this t-group (frag layout: 16 contiguous halves)
      const u16* vbp = &Vs[((tsub * 4 + quad) * 16 + l16) * 16];
      half8 v0 = *reinterpret_cast<const half8*>(vbp);
      half8 v1 = *reinterpret_cast<const half8*>(vbp + 8);
      half4 vb0 = __builtin_shufflevector(v0, v0, 0, 1, 2, 3);
      half4 vb1 = __builtin_shufflevector(v0, v0, 4, 5, 6, 7);
      half4 vb2 = __builtin_shufflevector(v1, v1, 0, 1, 2, 3);
      half4 vb3 = __builtin_shufflevector(v1, v1, 4, 5, 6, 7);

#pragma unroll
      for (int qi = 0; qi < 2; ++qi) {
        f32x4 s = __builtin_amdgcn_mfma_f32_16x16x32_bf16(k0f, qb[qi][0], fzero, 0, 0, 0);
        s = __builtin_amdgcn_mfma_f32_16x16x32_bf16(k1f, qb[qi][1], s, 0, 0, 0);
        float p0 = __builtin_amdgcn_exp2f(s[0]);
        float p1 = __builtin_amdgcn_exp2f(s[1]);
        float p2 = __builtin_amdgcn_exp2f(s[2]);
        float p3 = __builtin_amdgcn_exp2f(s[3]);
        l_acc[qi] += (p0 + p1) + (p2 + p3);
        half4 pa;
        pa[0] = (_Float16)p0; pa[1] = (_Float16)p1;
        pa[2] = (_Float16)p2; pa[3] = (_Float16)p3;
        o_acc[qi][0] = __builtin_amdgcn_mfma_f32_16x16x16f16(pa, vb0, o_acc[qi][0], 0, 0, 0);
        o_acc[qi][1] = __builtin_amdgcn_mfma_f32_16x16x16f16(pa, vb1, o_acc[qi][1], 0, 0, 0);
        o_acc[qi][2] = __builtin_amdgcn_mfma_f32_16x16x16f16(pa, vb2, o_acc[qi][2], 0, 0, 0);
        o_acc[qi][3] = __builtin_amdgcn_mfma_f32_16x16x16f16(pa, vb3, o_acc[qi][3], 0, 0, 0);
      }
    }
  }

  // l: reduce across quads -> every lane holds l for q = l16 (this wave's qi)
#pragma unroll
  for (int qi = 0; qi < 2; ++qi) {
    l_acc[qi] += __shfl_xor(l_acc[qi], 16, 64);
    l_acc[qi] += __shfl_xor(l_acc[qi], 32, 64);
  }

  // epilogue: wave-local. O C-layout: row (q) = quad*4+r, col (d) = nd*16+l16.
  // l lives at lane l16 == q -> fetch l[quad*4+r] via per-lane shfl.
  const int b = bh >> 4, h = bh & 15;
#pragma unroll
  for (int qi = 0; qi < 2; ++qi) {
    float lv[4];
#pragma unroll
    for (int r = 0; r < 4; ++r)
      lv[r] = __shfl(l_acc[qi], quad * 4 + r, 64);
#pragma unroll
    for (int nd = 0; nd < 4; ++nd) {
#pragma unroll
      for (int r = 0; r < 4; ++r) {
        int sq = q0 + w * 32 + qi * 16 + quad * 4 + r;
        o_buf[(size_t)(b * 2048 + sq) * 1024 + h * 64 + nd * 16 + l16] =
            f2bf(o_acc[qi][nd][r] / lv[r]);
      }
    }
  }
}

extern "C" void kernel_launch(void* const* d_in, const int* in_sizes, int n_in,
                              void* d_out, int out_size, void* d_ws, size_t ws_size,
                              hipStream_t stream) {
  (void)in_sizes; (void)n_in; (void)out_size; (void)ws_size;
  const float* x     = (const float*)d_in[0];
  const float* W_qkv = (const float*)d_in[1];
  const float* b_qkv = (const float*)d_in[2];
  const float* W_out = (const float*)d_in[3];
  const float* b_out = (const float*)d_in[4];
  float* out = (float*)d_out;

  // workspace layout (48 MB total)
  char* ws = (char*)d_ws;
  u16* x_bf   = (u16*)(ws);              //  8 MB  [4096][1024] bf16
  u16* wqkv_t = (u16*)(ws + 8388608);    //  6 MB  [3072][1024] bf16
  u16* wout_t = (u16*)(ws + 14680064);   //  2 MB  [1024][1024] bf16
  u16* q_buf  = (u16*)(ws + 16777216);   //  8 MB  [32][2048][64] bf16
  u16* k_buf  = (u16*)(ws + 25165824);   //  8 MB  [32][2048][64] bf16
  u16* vt_buf = (u16*)(ws + 33554432);   //  8 MB  [32] V-frag fp16 layout
  u16* o_bf   = (u16*)(ws + 41943040);   //  8 MB  [4096][1024] bf16

  cvt_x<<<4096, 256, 0, stream>>>(x, x_bf);
  transpose_w<<<dim3(96, 32), 256, 0, stream>>>(W_qkv, wqkv_t, 1024, 3072);
  transpose_w<<<dim3(32, 32), 256, 0, stream>>>(W_out, wout_t, 1024, 1024);
  gemm_bt<0, 4><<<dim3(24, 32), 256, 0, stream>>>(x_bf, wqkv_t, b_qkv, nullptr,
                                                  q_buf, k_buf, vt_buf, 4096, 3072, 1024);
  attn<<<dim3(32, 16), 256, 0, stream>>>(q_buf, k_buf, vt_buf, o_bf);
  gemm_bt<1, 2><<<dim3(8, 64), 256, 0, stream>>>(o_bf, wout_t, b_out, out,
                                                 nullptr, nullptr, nullptr, 4096, 1024, 1024);
}

// Round 5
// 188.649 us; speedup vs baseline: 1.8962x; 1.0226x over previous
//
#include <hip/hip_runtime.h>

typedef unsigned short u16;
typedef unsigned int   u32;

using short8 = __attribute__((ext_vector_type(8))) short;
using f32x4  = __attribute__((ext_vector_type(4))) float;
using half4  = __attribute__((ext_vector_type(4))) _Float16;
using half8  = __attribute__((ext_vector_type(8))) _Float16;

// SCALE * log2(e) folded into q at the QKV epilogue
#define QSCALE 0.18033688011112042f

__device__ __forceinline__ u16 f2bf(float f) {
  u32 u = __float_as_uint(f);
  return (u16)((u + 0x8000u) >> 16);
}
__device__ __forceinline__ u16 f2h(float f) {
  _Float16 h = (_Float16)f;
  return __builtin_bit_cast(u16, h);
}

// async global->LDS DMA, 16B per lane; lds dest = wave-uniform base + lane*16
__device__ __forceinline__ void gld16(const u16* g, u16* l) {
  __builtin_amdgcn_global_load_lds(
      (const __attribute__((address_space(1))) unsigned int*)g,
      (__attribute__((address_space(3))) unsigned int*)l, 16, 0, 0);
}

// ---------------- x fp32 -> bf16, 4 elems/thread ----------------
__global__ __launch_bounds__(256) void cvt_x(const float* __restrict__ in,
                                             u16* __restrict__ out) {
  int idx = blockIdx.x * 256 + threadIdx.x;
  float4 v = reinterpret_cast<const float4*>(in)[idx];
  ushort4 o;
  o.x = f2bf(v.x); o.y = f2bf(v.y); o.z = f2bf(v.z); o.w = f2bf(v.w);
  reinterpret_cast<ushort4*>(out)[idx] = o;
}

// ---------------- fp32 [R][C] -> bf16 [C][R] (B^T layout for GEMM) ----------------
__global__ __launch_bounds__(256) void transpose_w(const float* __restrict__ in,
                                                   u16* __restrict__ out,
                                                   int R, int C) {
  __shared__ u32 s[32][33];
  int c0 = blockIdx.x * 32, r0 = blockIdx.y * 32;
  int j = threadIdx.x & 31, i0 = threadIdx.x >> 5;
#pragma unroll
  for (int p = 0; p < 4; ++p) {
    int i = i0 + p * 8;
    s[i][j] = f2bf(in[(size_t)(r0 + i) * C + c0 + j]);
  }
  __syncthreads();
#pragma unroll
  for (int p = 0; p < 4; ++p) {
    int jj = i0 + p * 8;
    out[(size_t)(c0 + jj) * R + r0 + j] = (u16)s[j][jj];
  }
}

// ---------------- bf16 MFMA GEMM: C[M,N] = A[M,K] @ Bt[N,K]^T + bias ----------------
// m97 structure, block tile (32*MT) x 128, BK=32, global_load_lds width-16
// staging with XOR-swizzled LDS. EPI==0 (MT=4): scatter qkv (q pre-scaled by
// SCALE*log2e; v written fp16 in 16-half-contiguous frag layout:
// off = ((t>>2)*16 + (d&15))*16 + (d>>4)*4 + (t&3)). EPI==1 (MT=2): fp32 C out.
template <int EPI, int MT>
__global__ __launch_bounds__(256, 3) void gemm_bt(
    const u16* __restrict__ A, const u16* __restrict__ Bt,
    const float* __restrict__ bias, float* __restrict__ c_out,
    u16* __restrict__ q_out, u16* __restrict__ k_out, u16* __restrict__ vt_out,
    int M, int N, int K) {
  __shared__ __align__(16) u16 As[32 * MT * 32];
  __shared__ __align__(16) u16 Bs[128 * 32];
  const int tid = threadIdx.x;
  const int lane = tid & 63;
  const int wv = tid >> 6;
  const int l16 = lane & 15, quad = lane >> 4;
  const int wm = wv & 1, wn = wv >> 1;
  const int bx = blockIdx.x, by = blockIdx.y;

  const u16* Ab = A + (size_t)by * (32 * MT) * K;
  const u16* Bb = Bt + (size_t)bx * 128 * K;

  const f32x4 fzero = {0.0f, 0.0f, 0.0f, 0.0f};
  f32x4 acc[MT][4];
#pragma unroll
  for (int i = 0; i < MT; ++i)
#pragma unroll
    for (int j = 0; j < 4; ++j) acc[i][j] = fzero;

  for (int k0 = 0; k0 < K; k0 += 32) {
    __syncthreads();
#pragma unroll
    for (int p = 0; p < MT / 2; ++p) {
      int id = p * 256 + tid;
      int row = id >> 2, blk = id & 3;
      int gc = k0 + ((blk ^ (row & 3)) << 3);
      gld16(Ab + (size_t)row * K + gc, &As[id << 3]);
    }
#pragma unroll
    for (int p = 0; p < 2; ++p) {
      int id = p * 256 + tid;
      int row = id >> 2, blk = id & 3;
      int gc = k0 + ((blk ^ (row & 3)) << 3);
      gld16(Bb + (size_t)row * K + gc, &Bs[id << 3]);
    }
    __syncthreads();
    short8 af[MT], bfr[4];
#pragma unroll
    for (int mi = 0; mi < MT; ++mi) {
      int row = wm * (MT * 16) + mi * 16 + l16;
      af[mi] = *reinterpret_cast<const short8*>(&As[row * 32 + ((quad ^ (row & 3)) << 3)]);
    }
#pragma unroll
    for (int ni = 0; ni < 4; ++ni) {
      int row = wn * 64 + ni * 16 + l16;
      bfr[ni] = *reinterpret_cast<const short8*>(&Bs[row * 32 + ((quad ^ (row & 3)) << 3)]);
    }
#pragma unroll
    for (int mi = 0; mi < MT; ++mi)
#pragma unroll
      for (int ni = 0; ni < 4; ++ni)
        acc[mi][ni] = __builtin_amdgcn_mfma_f32_16x16x32_bf16(af[mi], bfr[ni], acc[mi][ni], 0, 0, 0);
  }

  // epilogue: C row = quad*4+r (A dim), col = l16 (B dim)
#pragma unroll
  for (int mi = 0; mi < MT; ++mi)
#pragma unroll
    for (int ni = 0; ni < 4; ++ni) {
      int col = bx * 128 + wn * 64 + ni * 16 + l16;
      float bv = bias[col];
      int row0 = by * (32 * MT) + wm * (MT * 16) + mi * 16 + quad * 4;
      if (EPI == 1) {
#pragma unroll
        for (int r = 0; r < 4; ++r)
          c_out[(size_t)(row0 + r) * N + col] = acc[mi][ni][r] + bv;
      } else {
        int which = col >> 10, rem = col & 1023;
        int h = rem >> 6, d = rem & 63;
        int b = row0 >> 11, sq0 = row0 & 2047;
        int bh = (b << 4) + h;
        if (which == 2) {
          // V fp16 frag layout: 4 consecutive t -> one 8B store
          ushort4 pk;
          pk.x = f2h(acc[mi][ni][0] + bv);
          pk.y = f2h(acc[mi][ni][1] + bv);
          pk.z = f2h(acc[mi][ni][2] + bv);
          pk.w = f2h(acc[mi][ni][3] + bv);
          size_t off = (size_t)bh * 131072 +
                       (((sq0 >> 2) * 16 + (d & 15)) * 16 + ((d >> 4) << 2));
          *reinterpret_cast<ushort4*>(&vt_out[off]) = pk;
        } else {
          size_t base = (size_t)(bh * 2048 + sq0) * 64 + d;
#pragma unroll
          for (int r = 0; r < 4; ++r) {
            float val = acc[mi][ni][r] + bv;
            if (which == 0) q_out[base + r * 64] = f2bf(val * QSCALE);
            else            k_out[base + r * 64] = f2bf(val);
          }
        }
      }
    }
}

// ---------------- flash attention (q-split waves, double-buffered LDS K/V) --
// 128 Q rows/block, 4 waves: wave w owns q-rows [w*32, w*32+32) and computes
// their COMPLETE output. Each 64-t K/V tile staged ONCE per block into LDS.
// Pipeline (T3-lite): per iter {issue next-tile gld16 -> compute current tile
// -> ONE barrier}. Staging loads stay in flight across the whole compute
// phase, so the vmcnt drain at the barrier is covered (r4 exposed ~450cyc/iter
// on a stage->drain->compute sequence).
// Bank conflicts: K rows XOR-swizzled (verified even 8-lanes/bank-set). V
// granules (16B) swizzled with involution g^=(g>>4)&1 via PRE-SWIZZLED GLOBAL
// source + linear gld16 dest (rule: both-sides-or-neither); read applies the
// same XOR -> v0/v1 ds_read_b128 spread over all 8 bank-sets (r4's linear V
// hit only 4 sets = 2x serialization, the measured 2.1M conflicts).
__global__ __launch_bounds__(256, 4) void attn(
    const u16* __restrict__ q_buf, const u16* __restrict__ k_buf,
    const u16* __restrict__ vt_buf, u16* __restrict__ o_buf) {
  __shared__ __align__(16) u16 Ks[2][4096];  // 2 x 8 KB, rows XOR-swizzled
  __shared__ __align__(16) u16 Vs[2][4096];  // 2 x 8 KB, granule-swizzled

  const int tid = threadIdx.x;
  const int lane = tid & 63, w = tid >> 6;
  const int l16 = lane & 15, quad = lane >> 4;
  const int bh = blockIdx.x, q0 = blockIdx.y * 128;

  const u16* qg = q_buf + (size_t)bh * 131072 + (q0 + w * 32) * 64;
  const u16* kg = k_buf + (size_t)bh * 131072;
  const u16* vg = vt_buf + (size_t)bh * 131072;

  // Q B-frags (loop-invariant): per qi tile col=q=l16, k = kk*32 + quad*8 + j
  short8 qb[2][2];
#pragma unroll
  for (int qi = 0; qi < 2; ++qi)
#pragma unroll
    for (int kk = 0; kk < 2; ++kk)
      qb[qi][kk] = *reinterpret_cast<const short8*>(
          qg + (qi * 16 + l16) * 64 + kk * 32 + quad * 8);

  const f32x4 fzero = {0.0f, 0.0f, 0.0f, 0.0f};
  f32x4 o_acc[2][4];
  float l_acc[2] = {0.f, 0.f};
#pragma unroll
  for (int qi = 0; qi < 2; ++qi)
#pragma unroll
    for (int nd = 0; nd < 4; ++nd) o_acc[qi][nd] = fzero;

  // stage tile t into LDS buffer bufid (2 x 16B chunks per thread per array)
  auto stage = [&](int bufid, const u16* kt, const u16* vt) {
#pragma unroll
    for (int p = 0; p < 2; ++p) {
      int id = p * 256 + tid;
      int krow = id >> 3, kblk = id & 7;
      gld16(kt + (size_t)krow * 64 + ((kblk ^ (krow & 7)) << 3),
            &Ks[bufid][id << 3]);
      int sj = id ^ ((id >> 4) & 1);  // involution: granule bit0 ^= bit4
      gld16(vt + ((size_t)sj << 3), &Vs[bufid][id << 3]);
    }
  };

  // prologue: stage tile 0
  stage(0, kg, vg);
  __syncthreads();

  for (int i = 0; i < 32; ++i) {
    const int cur = i & 1;
    if (i + 1 < 32)  // issue next-tile staging; completes during compute
      stage(cur ^ 1, kg + (size_t)(i + 1) * 4096, vg + (size_t)(i + 1) * 4096);

#pragma unroll
    for (int tsub = 0; tsub < 4; ++tsub) {
      // K A-frags: row rr = tsub*16 + l16, chunk (quad / quad+4) XOR (rr&7)
      int rr = tsub * 16 + l16;
      short8 k0f = *reinterpret_cast<const short8*>(
          &Ks[cur][rr * 64 + ((quad ^ (rr & 7)) << 3)]);
      short8 k1f = *reinterpret_cast<const short8*>(
          &Ks[cur][rr * 64 + (((4 + quad) ^ (rr & 7)) << 3)]);
      // V B-frags: logical granule base gb (even); slot = g ^ ((g>>4)&1),
      // (g>>4)&1 == (l16>>3)&1 for both granules of this pair
      int gb = (tsub * 4 + quad) * 32 + l16 * 2;
      int sw = (l16 >> 3) & 1;
      half8 v0 = *reinterpret_cast<const half8*>(&Vs[cur][(gb + sw) << 3]);
      half8 v1 = *reinterpret_cast<const half8*>(&Vs[cur][(gb + (sw ^ 1)) << 3]);
      half4 vb0 = __builtin_shufflevector(v0, v0, 0, 1, 2, 3);
      half4 vb1 = __builtin_shufflevector(v0, v0, 4, 5, 6, 7);
      half4 vb2 = __builtin_shufflevector(v1, v1, 0, 1, 2, 3);
      half4 vb3 = __builtin_shufflevector(v1, v1, 4, 5, 6, 7);

#pragma unroll
      for (int qi = 0; qi < 2; ++qi) {
        f32x4 s = __builtin_amdgcn_mfma_f32_16x16x32_bf16(k0f, qb[qi][0], fzero, 0, 0, 0);
        s = __builtin_amdgcn_mfma_f32_16x16x32_bf16(k1f, qb[qi][1], s, 0, 0, 0);
        float p0 = __builtin_amdgcn_exp2f(s[0]);
        float p1 = __builtin_amdgcn_exp2f(s[1]);
        float p2 = __builtin_amdgcn_exp2f(s[2]);
        float p3 = __builtin_amdgcn_exp2f(s[3]);
        l_acc[qi] += (p0 + p1) + (p2 + p3);
        half4 pa;
        pa[0] = (_Float16)p0; pa[1] = (_Float16)p1;
        pa[2] = (_Float16)p2; pa[3] = (_Float16)p3;
        o_acc[qi][0] = __builtin_amdgcn_mfma_f32_16x16x16f16(pa, vb0, o_acc[qi][0], 0, 0, 0);
        o_acc[qi][1] = __builtin_amdgcn_mfma_f32_16x16x16f16(pa, vb1, o_acc[qi][1], 0, 0, 0);
        o_acc[qi][2] = __builtin_amdgcn_mfma_f32_16x16x16f16(pa, vb2, o_acc[qi][2], 0, 0, 0);
        o_acc[qi][3] = __builtin_amdgcn_mfma_f32_16x16x16f16(pa, vb3, o_acc[qi][3], 0, 0, 0);
      }
    }
    __syncthreads();  // drains staging vmcnt (covered) + guards buffer reuse
  }

  // l: reduce across quads -> every lane holds l for q = l16 (this wave's qi)
#pragma unroll
  for (int qi = 0; qi < 2; ++qi) {
    l_acc[qi] += __shfl_xor(l_acc[qi], 16, 64);
    l_acc[qi] += __shfl_xor(l_acc[qi], 32, 64);
  }

  // epilogue: wave-local. O C-layout: row (q) = quad*4+r, col (d) = nd*16+l16.
  // l lives at lane l16 == q -> fetch l[quad*4+r] via per-lane shfl.
  const int b = bh >> 4, h = bh & 15;
#pragma unroll
  for (int qi = 0; qi < 2; ++qi) {
    float lv[4];
#pragma unroll
    for (int r = 0; r < 4; ++r)
      lv[r] = __shfl(l_acc[qi], quad * 4 + r, 64);
#pragma unroll
    for (int nd = 0; nd < 4; ++nd) {
#pragma unroll
      for (int r = 0; r < 4; ++r) {
        int sq = q0 + w * 32 + qi * 16 + quad * 4 + r;
        o_buf[(size_t)(b * 2048 + sq) * 1024 + h * 64 + nd * 16 + l16] =
            f2bf(o_acc[qi][nd][r] / lv[r]);
      }
    }
  }
}

extern "C" void kernel_launch(void* const* d_in, const int* in_sizes, int n_in,
                              void* d_out, int out_size, void* d_ws, size_t ws_size,
                              hipStream_t stream) {
  (void)in_sizes; (void)n_in; (void)out_size; (void)ws_size;
  const float* x     = (const float*)d_in[0];
  const float* W_qkv = (const float*)d_in[1];
  const float* b_qkv = (const float*)d_in[2];
  const float* W_out = (const float*)d_in[3];
  const float* b_out = (const float*)d_in[4];
  float* out = (float*)d_out;

  // workspace layout (48 MB total)
  char* ws = (char*)d_ws;
  u16* x_bf   = (u16*)(ws);              //  8 MB  [4096][1024] bf16
  u16* wqkv_t = (u16*)(ws + 8388608);    //  6 MB  [3072][1024] bf16
  u16* wout_t = (u16*)(ws + 14680064);   //  2 MB  [1024][1024] bf16
  u16* q_buf  = (u16*)(ws + 16777216);   //  8 MB  [32][2048][64] bf16
  u16* k_buf  = (u16*)(ws + 25165824);   //  8 MB  [32][2048][64] bf16
  u16* vt_buf = (u16*)(ws + 33554432);   //  8 MB  [32] V-frag fp16 layout
  u16* o_bf   = (u16*)(ws + 41943040);   //  8 MB  [4096][1024] bf16

  cvt_x<<<4096, 256, 0, stream>>>(x, x_bf);
  transpose_w<<<dim3(96, 32), 256, 0, stream>>>(W_qkv, wqkv_t, 1024, 3072);
  transpose_w<<<dim3(32, 32), 256, 0, stream>>>(W_out, wout_t, 1024, 1024);
  gemm_bt<0, 4><<<dim3(24, 32), 256, 0, stream>>>(x_bf, wqkv_t, b_qkv, nullptr,
                                                  q_buf, k_buf, vt_buf, 4096, 3072, 1024);
  attn<<<dim3(32, 16), 256, 0, stream>>>(q_buf, k_buf, vt_buf, o_bf);
  gemm_bt<1, 2><<<dim3(8, 64), 256, 0, stream>>>(o_bf, wout_t, b_out, out,
                                                 nullptr, nullptr, nullptr, 4096, 1024, 1024);
}